// Round 8
// baseline (247.124 us; speedup 1.0000x reference)
//
#include <hip/hip_runtime.h>
#include <hip/hip_fp16.h>

static constexpr float NEG_SLOPE = 0.2f;
#define BUCKET_BITS 7
#define BNODES (1 << BUCKET_BITS)      // 128 nodes per bucket
#define MAXNB 1024                     // supports n <= 131072 (src fits 17 bits)
#define MAXSUP 32                      // super-buckets (dst >> 12)
#define SUPER_SHIFT 12
#define CHUNK 8192
#define PTHREADS 512
#define SORT_CAP 6144                  // bucket-edge LDS staging capacity

__device__ __forceinline__ float4 h2x2_to_f4(float2 r) {
  __half2 a = __builtin_bit_cast(__half2, r.x);
  __half2 b = __builtin_bit_cast(__half2, r.y);
  float2 fa = __half22float2(a), fb = __half22float2(b);
  return make_float4(fa.x, fa.y, fb.x, fb.y);
}

// ------- Layer-1 node transform: per-head fp16 tables + per-head a_src -----
__global__ void k_node1(const float* __restrict__ x,
                        const float* __restrict__ w1,    // [3,32]
                        const float* __restrict__ atts,  // [2,16]
                        const float* __restrict__ attd,  // [2,16]
                        __half2* __restrict__ xh0,       // [N,8] half2 (head0)
                        __half2* __restrict__ xh1,       // [N,8] half2 (head1)
                        float* __restrict__ as0,         // [N]
                        float* __restrict__ as1,         // [N]
                        float* __restrict__ ad_,         // [N,2]
                        int n) {
  int i = blockIdx.x * blockDim.x + threadIdx.x;
  if (i >= n) return;
  float x0 = x[3*i], x1 = x[3*i+1], x2 = x[3*i+2];
  float v[32];
#pragma unroll
  for (int j = 0; j < 32; ++j)
    v[j] = fmaf(x0, w1[j], fmaf(x1, w1[32+j], x2 * w1[64+j]));
  float s0=0.f, s1=0.f, d0=0.f, d1=0.f;
#pragma unroll
  for (int k = 0; k < 16; ++k) {
    s0 = fmaf(v[k],    atts[k],    s0);
    d0 = fmaf(v[k],    attd[k],    d0);
    s1 = fmaf(v[16+k], atts[16+k], s1);
    d1 = fmaf(v[16+k], attd[16+k], d1);
  }
  __half2* o0 = xh0 + (size_t)i*8;
  __half2* o1 = xh1 + (size_t)i*8;
#pragma unroll
  for (int q = 0; q < 8; ++q) {
    o0[q] = __floats2half2_rn(v[2*q],      v[2*q+1]);
    o1[q] = __floats2half2_rn(v[16+2*q],   v[16+2*q+1]);
  }
  as0[i] = s0; as1[i] = s1;
  ad_[2*i] = d0; ad_[2*i+1] = d1;
}

// ---------------- 1024-bin bucket histogram (single edst pass) -------------
__global__ void k_hist1024(const int* __restrict__ edst, unsigned* __restrict__ gcount,
                           int E, int nb) {
  __shared__ unsigned hist[MAXNB];
  for (int b = threadIdx.x; b < MAXNB; b += blockDim.x) hist[b] = 0u;
  __syncthreads();
  int stride = gridDim.x * blockDim.x;
  for (int e = blockIdx.x * blockDim.x + threadIdx.x; e < E; e += stride)
    atomicAdd(&hist[((unsigned)edst[e]) >> BUCKET_BITS], 1u);
  __syncthreads();
  for (int b = threadIdx.x; b < nb; b += blockDim.x)
    if (hist[b]) atomicAdd(&gcount[b], hist[b]);
}

// -------- One scan: bucket starts/cursors AND super starts/cursors ---------
__global__ void k_scanall(const unsigned* __restrict__ gcount,
                          unsigned* __restrict__ bstart, unsigned* __restrict__ bcur,
                          unsigned* __restrict__ sstart, unsigned* __restrict__ scur,
                          int nb) {
  __shared__ unsigned sm[MAXNB];
  __shared__ unsigned ex[MAXNB];
  int t = threadIdx.x;
  unsigned v = (t < nb) ? gcount[t] : 0u;
  sm[t] = v; __syncthreads();
  for (int off = 1; off < MAXNB; off <<= 1) {
    unsigned u = (t >= off) ? sm[t - off] : 0u;
    __syncthreads();
    sm[t] += u;
    __syncthreads();
  }
  unsigned excl = sm[t] - v;
  ex[t] = excl;
  bstart[t] = excl;
  if (t < nb) bcur[t] = excl;
  __syncthreads();
  if (t < MAXSUP) { unsigned e2 = ex[t << 5]; sstart[t] = e2; scur[t] = e2; }
  if (t == 0) sstart[MAXSUP] = sm[MAXNB - 1];
}

// ---------------- Pass 1: distribute edges by super (32 bins) --------------
__global__ void k_part1(const int* __restrict__ esrc, const int* __restrict__ edst,
                        unsigned* __restrict__ scur, unsigned* __restrict__ tmp1,
                        int E) {
  __shared__ unsigned shist[MAXSUP], sbase[MAXSUP], soffs[MAXSUP];
  int t = threadIdx.x;
  if (t < MAXSUP) { shist[t] = 0u; soffs[t] = 0u; }
  __syncthreads();
  int e0 = blockIdx.x * CHUNK;
  int e1 = min(E, e0 + CHUNK);
  for (int e = e0 + t; e < e1; e += PTHREADS)
    atomicAdd(&shist[((unsigned)edst[e]) >> SUPER_SHIFT], 1u);
  __syncthreads();
  if (t < MAXSUP) sbase[t] = shist[t] ? atomicAdd(&scur[t], shist[t]) : 0u;
  __syncthreads();
  for (int e = e0 + t; e < e1; e += PTHREADS) {
    unsigned d = (unsigned)edst[e];
    unsigned hi = d >> SUPER_SHIFT;
    unsigned pk = (((d >> BUCKET_BITS) & 31u) << 24)
                | ((d & (BNODES - 1u)) << 17) | (unsigned)esrc[e];
    unsigned r = atomicAdd(&soffs[hi], 1u);
    tmp1[sbase[hi] + r] = pk;
  }
}

// ---------------- Pass 2: within super, distribute by b_lo (32 bins) -------
__global__ void k_part2(const unsigned* __restrict__ tmp1,
                        const unsigned* __restrict__ sstart, // [MAXSUP+1]
                        unsigned* __restrict__ bcur,
                        unsigned* __restrict__ packed2,
                        int E, int nb) {
  __shared__ unsigned stage[CHUNK];
  __shared__ unsigned sst[MAXSUP + 1];
  __shared__ unsigned hist[4*32], base[4*32], offs[4*32];
  __shared__ int s0sh;
  int t = threadIdx.x;
  if (t <= MAXSUP) sst[t] = sstart[t];
  if (t < 128) { hist[t] = 0u; offs[t] = 0u; }
  __syncthreads();
  int e0 = blockIdx.x * CHUNK;
  int e1 = min(E, e0 + CHUNK);
  if (t == 0) {
    int s = 0;
    while (s + 1 < MAXSUP && (int)sst[s + 1] <= e0) ++s;
    s0sh = s;
  }
  __syncthreads();
  int s0 = s0sh;
  {
    int s = s0;
    for (int e = e0 + t; e < e1; e += PTHREADS) {
      while ((unsigned)e >= sst[s + 1]) ++s;
      unsigned pk = tmp1[e];
      int ds = s - s0;
      if (ds < 4) {
        atomicAdd(&hist[(ds << 5) | (pk >> 24)], 1u);
        stage[e - e0] = pk | ((unsigned)ds << 29);
      } else {
        unsigned b = ((unsigned)s << 5) | (pk >> 24);
        unsigned slot = atomicAdd(&bcur[b], 1u);
        packed2[slot] = pk & 0x00FFFFFFu;
        stage[e - e0] = 0xFFFFFFFFu;
      }
    }
  }
  __syncthreads();
  if (t < 128) {
    unsigned b = (((unsigned)(s0 + (t >> 5))) << 5) | (t & 31u);
    if (hist[t] && b < (unsigned)nb)
      base[t] = atomicAdd(&bcur[b], hist[t]);
  }
  __syncthreads();
  for (int e = e0 + t; e < e1; e += PTHREADS) {
    unsigned v = stage[e - e0];
    unsigned ds = v >> 29;
    if (ds < 4u) {
      unsigned idx = (ds << 5) | ((v >> 24) & 31u);
      unsigned r = atomicAdd(&offs[idx], 1u);
      packed2[base[idx] + r] = v & 0x00FFFFFFu;
    }
  }
}

// ---------------- Per-bucket LDS sort: bucket run -> node-sorted col + rp --
__global__ void k_sortb(const unsigned* __restrict__ bstart,
                        const unsigned* __restrict__ packed,
                        int* __restrict__ col,
                        unsigned* __restrict__ rp,
                        int n) {
  __shared__ unsigned stage_in[SORT_CAP];
  __shared__ unsigned stage_out[SORT_CAP];
  __shared__ unsigned cnt[BNODES], sm[BNODES], excl[BNODES], off[BNODES];
  int b = blockIdx.x;
  unsigned s0 = bstart[b], s1 = bstart[b + 1];
  int size = (int)(s1 - s0);
  int t = threadIdx.x;
  if (t < BNODES) cnt[t] = 0u;
  __syncthreads();
  bool lds_path = (size <= SORT_CAP);
  if (lds_path) {
    for (int i = t; i < size; i += blockDim.x) {
      unsigned pk = packed[s0 + i];
      stage_in[i] = pk;
      atomicAdd(&cnt[pk >> 17], 1u);
    }
  } else {
    for (int i = t; i < size; i += blockDim.x)
      atomicAdd(&cnt[packed[s0 + i] >> 17], 1u);
  }
  __syncthreads();
  // parallel inclusive scan over 128 bins -> exclusive
  if (t < BNODES) sm[t] = cnt[t];
  __syncthreads();
#pragma unroll
  for (int offi = 1; offi < BNODES; offi <<= 1) {
    unsigned u = (t < BNODES && t >= offi) ? sm[t - offi] : 0u;
    __syncthreads();
    if (t < BNODES) sm[t] += u;
    __syncthreads();
  }
  if (t < BNODES) { excl[t] = sm[t] - cnt[t]; off[t] = sm[t] - cnt[t]; }
  __syncthreads();
  if (lds_path) {
    for (int i = t; i < size; i += blockDim.x) {
      unsigned pk = stage_in[i];
      unsigned slot = atomicAdd(&off[pk >> 17], 1u);
      stage_out[slot] = pk & 0x1FFFFu;
    }
    __syncthreads();
    for (int i = t; i < size; i += blockDim.x)
      col[s0 + i] = (int)stage_out[i];
  } else {
    for (int i = t; i < size; i += blockDim.x) {
      unsigned pk = packed[s0 + i];
      unsigned slot = atomicAdd(&off[pk >> 17], 1u);
      col[s0 + slot] = (int)(pk & 0x1FFFFu);
    }
  }
  int base = b << BUCKET_BITS;
  if (t < BNODES && base + t < n) rp[base + t] = s0 + excl[t];
}

// --- Per-head gather: 4 lanes/node, 4 ch/lane; head table is L2-resident ---
__global__ void k_gatherH(const unsigned* __restrict__ rp,
                          const int* __restrict__ col,
                          const float2* __restrict__ xh,  // [N,4] f2 = 32B/row
                          const float* __restrict__ ash,  // [N] (this head)
                          const float* __restrict__ ad_,  // [N,2]
                          float4* __restrict__ num,       // [N,8] float4
                          float* __restrict__ den,        // [N,2]
                          int h, int n, int E) {
  constexpr int LPE = 4;
  int d = blockIdx.x * (blockDim.x / LPE) + threadIdx.x / LPE;
  int lane = threadIdx.x & (LPE - 1);
  if (d >= n) return;
  float adh = ad_[2*d + h];
  float4 acc = make_float4(0.f, 0.f, 0.f, 0.f);
  float dsum = 0.f;
  unsigned jb = rp[d];
  unsigned je = (d + 1 < n) ? rp[d + 1] : (unsigned)E;
  unsigned j = jb;
  for (; j + 4 <= je; j += 4) {
    int s0 = col[j], s1 = col[j+1], s2 = col[j+2], s3 = col[j+3];
    float b0 = ash[s0], b1 = ash[s1], b2 = ash[s2], b3 = ash[s3];
    float2 r0 = xh[(size_t)s0*LPE + lane];
    float2 r1 = xh[(size_t)s1*LPE + lane];
    float2 r2 = xh[(size_t)s2*LPE + lane];
    float2 r3 = xh[(size_t)s3*LPE + lane];
    float a;
    a = b0 + adh; a = (a >= 0.f) ? a : NEG_SLOPE*a; float e0 = __expf(a);
    a = b1 + adh; a = (a >= 0.f) ? a : NEG_SLOPE*a; float e1 = __expf(a);
    a = b2 + adh; a = (a >= 0.f) ? a : NEG_SLOPE*a; float e2 = __expf(a);
    a = b3 + adh; a = (a >= 0.f) ? a : NEG_SLOPE*a; float e3 = __expf(a);
    float4 f;
    f = h2x2_to_f4(r0);
    acc.x = fmaf(f.x,e0,acc.x); acc.y = fmaf(f.y,e0,acc.y);
    acc.z = fmaf(f.z,e0,acc.z); acc.w = fmaf(f.w,e0,acc.w);
    f = h2x2_to_f4(r1);
    acc.x = fmaf(f.x,e1,acc.x); acc.y = fmaf(f.y,e1,acc.y);
    acc.z = fmaf(f.z,e1,acc.z); acc.w = fmaf(f.w,e1,acc.w);
    f = h2x2_to_f4(r2);
    acc.x = fmaf(f.x,e2,acc.x); acc.y = fmaf(f.y,e2,acc.y);
    acc.z = fmaf(f.z,e2,acc.z); acc.w = fmaf(f.w,e2,acc.w);
    f = h2x2_to_f4(r3);
    acc.x = fmaf(f.x,e3,acc.x); acc.y = fmaf(f.y,e3,acc.y);
    acc.z = fmaf(f.z,e3,acc.z); acc.w = fmaf(f.w,e3,acc.w);
    dsum += (e0 + e1) + (e2 + e3);
  }
  for (; j < je; ++j) {
    int s = col[j];
    float a = ash[s] + adh;
    a = (a >= 0.f) ? a : NEG_SLOPE*a;
    float ee = __expf(a);
    float4 f = h2x2_to_f4(xh[(size_t)s*LPE + lane]);
    acc.x = fmaf(f.x,ee,acc.x); acc.y = fmaf(f.y,ee,acc.y);
    acc.z = fmaf(f.z,ee,acc.z); acc.w = fmaf(f.w,ee,acc.w);
    dsum += ee;
  }
  num[(size_t)d*8 + h*4 + lane] = acc;
  if (lane == 0) den[2*d + h] = dsum;
}

// ------- Gather L2 fused with finalize: LPE=4, shfl head-mean+log_softmax --
__global__ void k_gather_final(const unsigned* __restrict__ rp,
                               const int* __restrict__ col,
                               const float2* __restrict__ xl2, // [N,4] f2 (pad16)
                               const float* __restrict__ as_,  // [N,2]
                               const float* __restrict__ ad_,  // [N,2]
                               const float* __restrict__ b2,   // [7]
                               float* __restrict__ out,        // [N,7]
                               int n, int E) {
  constexpr int LPE = 4;
  int d = blockIdx.x * (blockDim.x / LPE) + threadIdx.x / LPE;
  int lane = threadIdx.x & (LPE - 1);
  if (d >= n) return;
  int h = lane >> 1;
  float adh = ad_[2*d + h];
  float4 acc = make_float4(0.f, 0.f, 0.f, 0.f);
  float dsum = 0.f;
  unsigned jb = rp[d];
  unsigned je = (d + 1 < n) ? rp[d + 1] : (unsigned)E;
  unsigned j = jb;
  for (; j + 4 <= je; j += 4) {
    int s0 = col[j], s1 = col[j+1], s2 = col[j+2], s3 = col[j+3];
    float b0 = as_[2*s0 + h], b1 = as_[2*s1 + h],
          b2v = as_[2*s2 + h], b3 = as_[2*s3 + h];
    float2 r0 = xl2[(size_t)s0*LPE + lane];
    float2 r1 = xl2[(size_t)s1*LPE + lane];
    float2 r2 = xl2[(size_t)s2*LPE + lane];
    float2 r3 = xl2[(size_t)s3*LPE + lane];
    float a;
    a = b0  + adh; a = (a >= 0.f) ? a : NEG_SLOPE*a; float e0 = __expf(a);
    a = b1  + adh; a = (a >= 0.f) ? a : NEG_SLOPE*a; float e1 = __expf(a);
    a = b2v + adh; a = (a >= 0.f) ? a : NEG_SLOPE*a; float e2 = __expf(a);
    a = b3  + adh; a = (a >= 0.f) ? a : NEG_SLOPE*a; float e3 = __expf(a);
    float4 f;
    f = h2x2_to_f4(r0);
    acc.x = fmaf(f.x,e0,acc.x); acc.y = fmaf(f.y,e0,acc.y);
    acc.z = fmaf(f.z,e0,acc.z); acc.w = fmaf(f.w,e0,acc.w);
    f = h2x2_to_f4(r1);
    acc.x = fmaf(f.x,e1,acc.x); acc.y = fmaf(f.y,e1,acc.y);
    acc.z = fmaf(f.z,e1,acc.z); acc.w = fmaf(f.w,e1,acc.w);
    f = h2x2_to_f4(r2);
    acc.x = fmaf(f.x,e2,acc.x); acc.y = fmaf(f.y,e2,acc.y);
    acc.z = fmaf(f.z,e2,acc.z); acc.w = fmaf(f.w,e2,acc.w);
    f = h2x2_to_f4(r3);
    acc.x = fmaf(f.x,e3,acc.x); acc.y = fmaf(f.y,e3,acc.y);
    acc.z = fmaf(f.z,e3,acc.z); acc.w = fmaf(f.w,e3,acc.w);
    dsum += (e0 + e1) + (e2 + e3);
  }
  for (; j < je; ++j) {
    int s = col[j];
    float a = as_[2*s + h] + adh;
    a = (a >= 0.f) ? a : NEG_SLOPE*a;
    float ee = __expf(a);
    float4 f = h2x2_to_f4(xl2[(size_t)s*LPE + lane]);
    acc.x = fmaf(f.x,ee,acc.x); acc.y = fmaf(f.y,ee,acc.y);
    acc.z = fmaf(f.z,ee,acc.z); acc.w = fmaf(f.w,ee,acc.w);
    dsum += ee;
  }
  {  // self-loop
    float a = as_[2*d + h] + adh;
    a = (a >= 0.f) ? a : NEG_SLOPE*a;
    float ee = __expf(a);
    float4 f = h2x2_to_f4(xl2[(size_t)d*LPE + lane]);
    acc.x = fmaf(f.x,ee,acc.x); acc.y = fmaf(f.y,ee,acc.y);
    acc.z = fmaf(f.z,ee,acc.z); acc.w = fmaf(f.w,ee,acc.w);
    dsum += ee;
  }
  float dh = dsum + 1e-16f;
  float v[4];
  v[0] = acc.x / dh; v[1] = acc.y / dh; v[2] = acc.z / dh; v[3] = acc.w / dh;
  int chb = (lane & 1) * 4;
#pragma unroll
  for (int c = 0; c < 4; ++c) {
    float other = __shfl_xor(v[c], 2, 4);
    int ch = chb + c;
    v[c] = (ch < 7) ? (0.5f * (v[c] + other) + b2[ch]) : -1e30f;
  }
  float m = fmaxf(fmaxf(v[0], v[1]), fmaxf(v[2], v[3]));
  m = fmaxf(m, __shfl_xor(m, 1, 4));
  float s = __expf(v[0]-m) + __expf(v[1]-m) + __expf(v[2]-m) + __expf(v[3]-m);
  s += __shfl_xor(s, 1, 4);
  float ls = __logf(s);
  if (lane == 0) {
    float* o = out + (size_t)d*7;
    o[0] = v[0]-m-ls; o[1] = v[1]-m-ls; o[2] = v[2]-m-ls; o[3] = v[3]-m-ls;
  } else if (lane == 1) {
    float* o = out + (size_t)d*7;
    o[4] = v[0]-m-ls; o[5] = v[1]-m-ls; o[6] = v[2]-m-ls;
  }
}

// ---------------- L1 finalize (+self-loop) + ReLU + L2 transform -----------
__global__ void k_node2(const float* __restrict__ num1,  // [N,32]
                        const float* __restrict__ den1,  // [N,2]
                        const __half2* __restrict__ xh0, // [N,8]
                        const __half2* __restrict__ xh1, // [N,8]
                        const float* __restrict__ as0,   // [N]
                        const float* __restrict__ as1v,  // [N]
                        const float* __restrict__ ad1,   // [N,2]
                        const float* __restrict__ b1,    // [32]
                        const float* __restrict__ w2,    // [32,14]
                        const float* __restrict__ atts,  // [2,7]
                        const float* __restrict__ attd,  // [2,7]
                        __half2* __restrict__ xlh2,      // [N,8] padded (8/head)
                        float* __restrict__ as2,         // [N,2]
                        float* __restrict__ ad2,         // [N,2]
                        int n) {
  int i = blockIdx.x * blockDim.x + threadIdx.x;
  if (i >= n) return;
  float a0 = as0[i] + ad1[2*i];
  float a1 = as1v[i] + ad1[2*i+1];
  a0 = (a0 >= 0.f) ? a0 : NEG_SLOPE * a0;
  a1 = (a1 >= 0.f) ? a1 : NEG_SLOPE * a1;
  float e0 = __expf(a0), e1 = __expf(a1);
  float dh0 = den1[2*i]   + e0 + 1e-16f;
  float dh1 = den1[2*i+1] + e1 + 1e-16f;
  const float4* nr = reinterpret_cast<const float4*>(num1 + (size_t)i*32);
  const __half2* xr0 = xh0 + (size_t)i*8;
  const __half2* xr1 = xh1 + (size_t)i*8;
  float hbuf[32];
#pragma unroll
  for (int q = 0; q < 8; ++q) {
    float4 v = nr[q];
    const __half2* xr = (q < 4) ? xr0 : xr1;
    int qq = (q < 4) ? q : q - 4;
    float2 xa = __half22float2(xr[2*qq]);
    float2 xb = __half22float2(xr[2*qq+1]);
    float es = (q < 4) ? e0 : e1;
    float dd = (q < 4) ? dh0 : dh1;
    float t;
    t = (v.x + xa.x*es)/dd + b1[4*q];   hbuf[4*q]   = t > 0.f ? t : 0.f;
    t = (v.y + xa.y*es)/dd + b1[4*q+1]; hbuf[4*q+1] = t > 0.f ? t : 0.f;
    t = (v.z + xb.x*es)/dd + b1[4*q+2]; hbuf[4*q+2] = t > 0.f ? t : 0.f;
    t = (v.w + xb.y*es)/dd + b1[4*q+3]; hbuf[4*q+3] = t > 0.f ? t : 0.f;
  }
  float o[14];
#pragma unroll
  for (int j = 0; j < 14; ++j) o[j] = 0.f;
#pragma unroll
  for (int ch = 0; ch < 32; ++ch) {
#pragma unroll
    for (int j = 0; j < 14; ++j)
      o[j] = fmaf(hbuf[ch], w2[14*ch + j], o[j]);
  }
  float s0=0.f, s1=0.f, d0=0.f, d1=0.f;
#pragma unroll
  for (int k = 0; k < 7; ++k) {
    s0 = fmaf(o[k],   atts[k],   s0);
    d0 = fmaf(o[k],   attd[k],   d0);
    s1 = fmaf(o[7+k], atts[7+k], s1);
    d1 = fmaf(o[7+k], attd[7+k], d1);
  }
  __half2* xo = xlh2 + (size_t)i*8;
#pragma unroll
  for (int q = 0; q < 8; ++q) {
    int p0 = 2*q, p1 = 2*q+1;
    float v0 = ((p0 & 7) < 7) ? o[(p0 >> 3)*7 + (p0 & 7)] : 0.f;
    float v1 = ((p1 & 7) < 7) ? o[(p1 >> 3)*7 + (p1 & 7)] : 0.f;
    xo[q] = __floats2half2_rn(v0, v1);
  }
  as2[2*i] = s0; as2[2*i+1] = s1;
  ad2[2*i] = d0; ad2[2*i+1] = d1;
}

extern "C" void kernel_launch(void* const* d_in, const int* in_sizes, int n_in,
                              void* d_out, int out_size, void* d_ws, size_t ws_size,
                              hipStream_t stream) {
  const float* x    = (const float*)d_in[0];
  const int*   ei   = (const int*)  d_in[1];
  const float* w1   = (const float*)d_in[2];
  const float* as1w = (const float*)d_in[3];
  const float* ad1w = (const float*)d_in[4];
  const float* b1   = (const float*)d_in[5];
  const float* w2   = (const float*)d_in[6];
  const float* as2w = (const float*)d_in[7];
  const float* ad2w = (const float*)d_in[8];
  const float* b2   = (const float*)d_in[9];
  float* out = (float*)d_out;

  const int n = in_sizes[0] / 3;
  const int E = in_sizes[1] / 2;
  const int* esrc = ei;
  const int* edst = ei + E;
  const int nb = (n + BNODES - 1) >> BUCKET_BITS;   // 782 for n=100000

  const size_t N = (size_t)n;
  float* ws = (float*)d_ws;
  // workspace layout (4-byte units):
  __half2* xh0  = (__half2*)ws;                    //  8N  (head0 table)
  __half2* xh1  = (__half2*)(ws + 8*N);            //  8N  (head1 table)
  float* as0    = ws + 16*N;                       //   N
  float* as1h   = ws + 17*N;                       //   N
  float* ad1    = ws + 18*N;                       //  2N
  __half2* xlh2 = (__half2*)(ws + 20*N);           //  8N
  float* as2    = ws + 28*N;                       //  2N
  float* ad2    = ws + 30*N;                       //  2N
  float* num1   = ws + 32*N;                       // 32N
  float* den1   = ws + 64*N;                       //  2N -> 66N
  unsigned* ctrl   = (unsigned*)(ws + 66*N);
  unsigned* gcount = ctrl;                         // MAXNB+1
  unsigned* bstart = ctrl + (MAXNB + 1);           // MAXNB+1
  unsigned* bcur   = ctrl + 2*(MAXNB + 1);         // MAXNB+1
  unsigned* sstart = ctrl + 3*(MAXNB + 1);         // MAXSUP+1
  unsigned* scur   = sstart + (MAXSUP + 1);        // MAXSUP
  unsigned* rp     = scur + MAXSUP;                // N
  int*      col    = (int*)(rp + N);               // E
  unsigned* packed2= (unsigned*)(col + E);         // E
  unsigned* tmp1   = (unsigned*)num1;              // E (alias; E <= 32N)

  const int nbN = (n + 255) / 256;
  const int nbC = (E + CHUNK - 1) / CHUNK;

  hipMemsetAsync(gcount, 0, (MAXNB + 1) * sizeof(unsigned), stream);

  k_node1<<<nbN, 256, 0, stream>>>(x, w1, as1w, ad1w, xh0, xh1, as0, as1h, ad1, n);

  // two-level radix CSR build (shared by both layers)
  k_hist1024<<<512, 256, 0, stream>>>(edst, gcount, E, nb);
  k_scanall <<<1, MAXNB, 0, stream>>>(gcount, bstart, bcur, sstart, scur, nb);
  k_part1   <<<nbC, PTHREADS, 0, stream>>>(esrc, edst, scur, tmp1, E);
  k_part2   <<<nbC, PTHREADS, 0, stream>>>(tmp1, sstart, bcur, packed2, E, nb);
  k_sortb   <<<nb, 256, 0, stream>>>(bstart, packed2, col, rp, n);

  // Layer 1: per-head gather passes (each head table 3.2 MB -> L2-resident)
  k_gatherH<<<(n*4 + 255)/256, 256, 0, stream>>>(
      rp, col, (const float2*)xh0, as0, ad1, (float4*)num1, den1, 0, n, E);
  k_gatherH<<<(n*4 + 255)/256, 256, 0, stream>>>(
      rp, col, (const float2*)xh1, as1h, ad1, (float4*)num1, den1, 1, n, E);
  k_node2<<<nbN, 256, 0, stream>>>(num1, den1, xh0, xh1, as0, as1h, ad1, b1, w2,
                                   as2w, ad2w, xlh2, as2, ad2, n);

  // Layer 2: 4 lanes per node, 4 channels/lane, fused finalize
  k_gather_final<<<(n*4 + 255)/256, 256, 0, stream>>>(
      rp, col, (const float2*)xlh2, as2, ad2, b2, out, n, E);
}

// Round 9
// 167.920 us; speedup vs baseline: 1.4717x; 1.4717x over previous
//
#include <hip/hip_runtime.h>
#include <hip/hip_fp16.h>

static constexpr float NEG_SLOPE = 0.2f;
#define BUCKET_BITS 7
#define BNODES (1 << BUCKET_BITS)      // 128 nodes per bucket
#define MAXNB 1024                     // supports n <= 131072 (src fits 17 bits)
#define MAXSUP 32                      // super-buckets (dst >> 12)
#define SUPER_SHIFT 12
#define CHUNK 8192
#define PTHREADS 512
#define SORT_CAP 6144                  // bucket-edge LDS staging capacity

__device__ __forceinline__ float2 h2f(float r) {
  return __half22float2(__builtin_bit_cast(__half2, r));
}

// ------- Layer-1 node transform: packed x+as fp16 row (16B) + ad ----------
__global__ void k_node1(const float* __restrict__ x,
                        const float* __restrict__ w1,    // [3,32]
                        const float* __restrict__ atts,  // [2,16]
                        const float* __restrict__ attd,  // [2,16]
                        float4* __restrict__ xp,         // [N] {x0,x1,x2,as0,as1} fp16
                        float* __restrict__ ad_,         // [N,2]
                        int n) {
  int i = blockIdx.x * blockDim.x + threadIdx.x;
  if (i >= n) return;
  float x0 = x[3*i], x1 = x[3*i+1], x2 = x[3*i+2];
  float v[32];
#pragma unroll
  for (int j = 0; j < 32; ++j)
    v[j] = fmaf(x0, w1[j], fmaf(x1, w1[32+j], x2 * w1[64+j]));
  float s0=0.f, s1=0.f, d0=0.f, d1=0.f;
#pragma unroll
  for (int k = 0; k < 16; ++k) {
    s0 = fmaf(v[k],    atts[k],    s0);
    d0 = fmaf(v[k],    attd[k],    d0);
    s1 = fmaf(v[16+k], atts[16+k], s1);
    d1 = fmaf(v[16+k], attd[16+k], d1);
  }
  float4 r;
  r.x = __builtin_bit_cast(float, __floats2half2_rn(x0, x1));
  r.y = __builtin_bit_cast(float, __floats2half2_rn(x2, s0));
  r.z = __builtin_bit_cast(float, __floats2half2_rn(s1, 0.f));
  r.w = 0.f;
  xp[i] = r;
  ad_[2*i] = d0; ad_[2*i+1] = d1;
}

// ---------------- 1024-bin bucket histogram (single edst pass) -------------
__global__ void k_hist1024(const int* __restrict__ edst, unsigned* __restrict__ gcount,
                           int E, int nb) {
  __shared__ unsigned hist[MAXNB];
  for (int b = threadIdx.x; b < MAXNB; b += blockDim.x) hist[b] = 0u;
  __syncthreads();
  int stride = gridDim.x * blockDim.x;
  for (int e = blockIdx.x * blockDim.x + threadIdx.x; e < E; e += stride)
    atomicAdd(&hist[((unsigned)edst[e]) >> BUCKET_BITS], 1u);
  __syncthreads();
  for (int b = threadIdx.x; b < nb; b += blockDim.x)
    if (hist[b]) atomicAdd(&gcount[b], hist[b]);
}

// -------- One scan: bucket starts/cursors AND super starts/cursors ---------
__global__ void k_scanall(const unsigned* __restrict__ gcount,
                          unsigned* __restrict__ bstart, unsigned* __restrict__ bcur,
                          unsigned* __restrict__ sstart, unsigned* __restrict__ scur,
                          int nb) {
  __shared__ unsigned sm[MAXNB];
  __shared__ unsigned ex[MAXNB];
  int t = threadIdx.x;
  unsigned v = (t < nb) ? gcount[t] : 0u;
  sm[t] = v; __syncthreads();
  for (int off = 1; off < MAXNB; off <<= 1) {
    unsigned u = (t >= off) ? sm[t - off] : 0u;
    __syncthreads();
    sm[t] += u;
    __syncthreads();
  }
  unsigned excl = sm[t] - v;
  ex[t] = excl;
  bstart[t] = excl;
  if (t < nb) bcur[t] = excl;
  __syncthreads();
  if (t < MAXSUP) { unsigned e2 = ex[t << 5]; sstart[t] = e2; scur[t] = e2; }
  if (t == 0) sstart[MAXSUP] = sm[MAXNB - 1];
}

// ---------------- Pass 1: distribute edges by super (32 bins) --------------
__global__ void k_part1(const int* __restrict__ esrc, const int* __restrict__ edst,
                        unsigned* __restrict__ scur, unsigned* __restrict__ tmp1,
                        int E) {
  __shared__ unsigned shist[MAXSUP], sbase[MAXSUP], soffs[MAXSUP];
  int t = threadIdx.x;
  if (t < MAXSUP) { shist[t] = 0u; soffs[t] = 0u; }
  __syncthreads();
  int e0 = blockIdx.x * CHUNK;
  int e1 = min(E, e0 + CHUNK);
  for (int e = e0 + t; e < e1; e += PTHREADS)
    atomicAdd(&shist[((unsigned)edst[e]) >> SUPER_SHIFT], 1u);
  __syncthreads();
  if (t < MAXSUP) sbase[t] = shist[t] ? atomicAdd(&scur[t], shist[t]) : 0u;
  __syncthreads();
  for (int e = e0 + t; e < e1; e += PTHREADS) {
    unsigned d = (unsigned)edst[e];
    unsigned hi = d >> SUPER_SHIFT;
    unsigned pk = (((d >> BUCKET_BITS) & 31u) << 24)
                | ((d & (BNODES - 1u)) << 17) | (unsigned)esrc[e];
    unsigned r = atomicAdd(&soffs[hi], 1u);
    tmp1[sbase[hi] + r] = pk;
  }
}

// ---------------- Pass 2: within super, distribute by b_lo (32 bins) -------
__global__ void k_part2(const unsigned* __restrict__ tmp1,
                        const unsigned* __restrict__ sstart, // [MAXSUP+1]
                        unsigned* __restrict__ bcur,
                        unsigned* __restrict__ packed2,
                        int E, int nb) {
  __shared__ unsigned stage[CHUNK];
  __shared__ unsigned sst[MAXSUP + 1];
  __shared__ unsigned hist[4*32], base[4*32], offs[4*32];
  __shared__ int s0sh;
  int t = threadIdx.x;
  if (t <= MAXSUP) sst[t] = sstart[t];
  if (t < 128) { hist[t] = 0u; offs[t] = 0u; }
  __syncthreads();
  int e0 = blockIdx.x * CHUNK;
  int e1 = min(E, e0 + CHUNK);
  if (t == 0) {
    int s = 0;
    while (s + 1 < MAXSUP && (int)sst[s + 1] <= e0) ++s;
    s0sh = s;
  }
  __syncthreads();
  int s0 = s0sh;
  {
    int s = s0;
    for (int e = e0 + t; e < e1; e += PTHREADS) {
      while ((unsigned)e >= sst[s + 1]) ++s;
      unsigned pk = tmp1[e];
      int ds = s - s0;
      if (ds < 4) {
        atomicAdd(&hist[(ds << 5) | (pk >> 24)], 1u);
        stage[e - e0] = pk | ((unsigned)ds << 29);
      } else {
        unsigned b = ((unsigned)s << 5) | (pk >> 24);
        unsigned slot = atomicAdd(&bcur[b], 1u);
        packed2[slot] = pk & 0x00FFFFFFu;
        stage[e - e0] = 0xFFFFFFFFu;
      }
    }
  }
  __syncthreads();
  if (t < 128) {
    unsigned b = (((unsigned)(s0 + (t >> 5))) << 5) | (t & 31u);
    if (hist[t] && b < (unsigned)nb)
      base[t] = atomicAdd(&bcur[b], hist[t]);
  }
  __syncthreads();
  for (int e = e0 + t; e < e1; e += PTHREADS) {
    unsigned v = stage[e - e0];
    unsigned ds = v >> 29;
    if (ds < 4u) {
      unsigned idx = (ds << 5) | ((v >> 24) & 31u);
      unsigned r = atomicAdd(&offs[idx], 1u);
      packed2[base[idx] + r] = v & 0x00FFFFFFu;
    }
  }
}

// ---------------- Per-bucket LDS sort: bucket run -> node-sorted col + rp --
__global__ void k_sortb(const unsigned* __restrict__ bstart,
                        const unsigned* __restrict__ packed,
                        int* __restrict__ col,
                        unsigned* __restrict__ rp,
                        int n) {
  __shared__ unsigned stage_in[SORT_CAP];
  __shared__ unsigned stage_out[SORT_CAP];
  __shared__ unsigned cnt[BNODES], sm[BNODES], excl[BNODES], off[BNODES];
  int b = blockIdx.x;
  unsigned s0 = bstart[b], s1 = bstart[b + 1];
  int size = (int)(s1 - s0);
  int t = threadIdx.x;
  if (t < BNODES) cnt[t] = 0u;
  __syncthreads();
  bool lds_path = (size <= SORT_CAP);
  if (lds_path) {
    for (int i = t; i < size; i += blockDim.x) {
      unsigned pk = packed[s0 + i];
      stage_in[i] = pk;
      atomicAdd(&cnt[pk >> 17], 1u);
    }
  } else {
    for (int i = t; i < size; i += blockDim.x)
      atomicAdd(&cnt[packed[s0 + i] >> 17], 1u);
  }
  __syncthreads();
  if (t < BNODES) sm[t] = cnt[t];
  __syncthreads();
#pragma unroll
  for (int offi = 1; offi < BNODES; offi <<= 1) {
    unsigned u = (t < BNODES && t >= offi) ? sm[t - offi] : 0u;
    __syncthreads();
    if (t < BNODES) sm[t] += u;
    __syncthreads();
  }
  if (t < BNODES) { excl[t] = sm[t] - cnt[t]; off[t] = sm[t] - cnt[t]; }
  __syncthreads();
  if (lds_path) {
    for (int i = t; i < size; i += blockDim.x) {
      unsigned pk = stage_in[i];
      unsigned slot = atomicAdd(&off[pk >> 17], 1u);
      stage_out[slot] = pk & 0x1FFFFu;
    }
    __syncthreads();
    for (int i = t; i < size; i += blockDim.x)
      col[s0 + i] = (int)stage_out[i];
  } else {
    for (int i = t; i < size; i += blockDim.x) {
      unsigned pk = packed[s0 + i];
      unsigned slot = atomicAdd(&off[pk >> 17], 1u);
      col[s0 + slot] = (int)(pk & 0x1FFFFu);
    }
  }
  int base = b << BUCKET_BITS;
  if (t < BNODES && base + t < n) rp[base + t] = s0 + excl[t];
}

// ------ Layer-1 gather in x-space: 1 lane/node, both heads, unroll 4 ------
// numx[2d+h] = {Σ e_h x0, Σ e_h x1, Σ e_h x2, Σ e_h} over real edges only.
__global__ void k_gatherX(const unsigned* __restrict__ rp,
                          const int* __restrict__ col,
                          const float4* __restrict__ xp,  // [N] packed 16B
                          const float* __restrict__ ad_,  // [N,2]
                          float4* __restrict__ numx,      // [N,2]
                          int n, int E) {
  int d = blockIdx.x * blockDim.x + threadIdx.x;
  if (d >= n) return;
  float ad0 = ad_[2*d], ad1v = ad_[2*d+1];
  float4 a0 = make_float4(0.f,0.f,0.f,0.f);
  float4 a1 = make_float4(0.f,0.f,0.f,0.f);
  unsigned jb = rp[d];
  unsigned je = (d + 1 < n) ? rp[d + 1] : (unsigned)E;
  unsigned j = jb;

  auto proc = [&](float4 r) {
    float2 fx01 = h2f(r.x);          // x0, x1
    float2 fx2s = h2f(r.y);          // x2, as0
    float2 fs1  = h2f(r.z);          // as1, -
    float a = fx2s.y + ad0; a = (a >= 0.f) ? a : NEG_SLOPE*a;
    float e0 = __expf(a);
    a = fs1.x + ad1v; a = (a >= 0.f) ? a : NEG_SLOPE*a;
    float e1 = __expf(a);
    a0.x = fmaf(fx01.x, e0, a0.x); a0.y = fmaf(fx01.y, e0, a0.y);
    a0.z = fmaf(fx2s.x, e0, a0.z); a0.w += e0;
    a1.x = fmaf(fx01.x, e1, a1.x); a1.y = fmaf(fx01.y, e1, a1.y);
    a1.z = fmaf(fx2s.x, e1, a1.z); a1.w += e1;
  };

  for (; j + 4 <= je; j += 4) {
    int s0 = col[j], s1 = col[j+1], s2 = col[j+2], s3 = col[j+3];
    float4 r0 = xp[s0], r1 = xp[s1], r2 = xp[s2], r3 = xp[s3];
    proc(r0); proc(r1); proc(r2); proc(r3);
  }
  for (; j < je; ++j) proc(xp[col[j]]);
  numx[2*d]   = a0;
  numx[2*d+1] = a1;
}

// -- L1 finalize: reconstruct Wᵀ·numx + self-loop, ReLU, L2 transform, pack -
__global__ void k_node2(const float* __restrict__ x,     // [N,3]
                        const float4* __restrict__ numx, // [N,2]
                        const float* __restrict__ ad1,   // [N,2]
                        const float* __restrict__ w1,    // [3,32]
                        const float* __restrict__ atts1, // [2,16]
                        const float* __restrict__ attd1, // [2,16] (unused; ad1 stored)
                        const float* __restrict__ b1,    // [32]
                        const float* __restrict__ w2,    // [32,14]
                        const float* __restrict__ atts2, // [2,7]
                        const float* __restrict__ attd2, // [2,7]
                        float4* __restrict__ xl2p,       // [N,2] packed head rows
                        float* __restrict__ ad2,         // [N,2]
                        int n) {
  int i = blockIdx.x * blockDim.x + threadIdx.x;
  if (i >= n) return;
  float x0 = x[3*i], x1 = x[3*i+1], x2 = x[3*i+2];
  float v[32];
#pragma unroll
  for (int j = 0; j < 32; ++j)
    v[j] = fmaf(x0, w1[j], fmaf(x1, w1[32+j], x2 * w1[64+j]));
  float s0 = 0.f, s1 = 0.f;
#pragma unroll
  for (int k = 0; k < 16; ++k) {
    s0 = fmaf(v[k],    atts1[k],    s0);
    s1 = fmaf(v[16+k], atts1[16+k], s1);
  }
  float a0 = s0 + ad1[2*i];
  float a1 = s1 + ad1[2*i+1];
  a0 = (a0 >= 0.f) ? a0 : NEG_SLOPE * a0;
  a1 = (a1 >= 0.f) ? a1 : NEG_SLOPE * a1;
  float e0 = __expf(a0), e1 = __expf(a1);
  float4 nx0 = numx[2*i], nx1 = numx[2*i+1];
  float dh0 = nx0.w + e0 + 1e-16f;
  float dh1 = nx1.w + e1 + 1e-16f;
  float inv0 = 1.f / dh0, inv1 = 1.f / dh1;
  float hbuf[32];
#pragma unroll
  for (int j = 0; j < 16; ++j) {
    float nm = fmaf(nx0.x, w1[j], fmaf(nx0.y, w1[32+j], fmaf(nx0.z, w1[64+j], e0 * v[j])));
    float t = nm * inv0 + b1[j];
    hbuf[j] = t > 0.f ? t : 0.f;
  }
#pragma unroll
  for (int j = 0; j < 16; ++j) {
    int jj = 16 + j;
    float nm = fmaf(nx1.x, w1[jj], fmaf(nx1.y, w1[32+jj], fmaf(nx1.z, w1[64+jj], e1 * v[jj])));
    float t = nm * inv1 + b1[jj];
    hbuf[jj] = t > 0.f ? t : 0.f;
  }
  float o[14];
#pragma unroll
  for (int j = 0; j < 14; ++j) o[j] = 0.f;
#pragma unroll
  for (int ch = 0; ch < 32; ++ch) {
#pragma unroll
    for (int j = 0; j < 14; ++j)
      o[j] = fmaf(hbuf[ch], w2[14*ch + j], o[j]);
  }
  float t0=0.f, t1=0.f, d0=0.f, d1=0.f;
#pragma unroll
  for (int k = 0; k < 7; ++k) {
    t0 = fmaf(o[k],   atts2[k],   t0);
    d0 = fmaf(o[k],   attd2[k],   d0);
    t1 = fmaf(o[7+k], atts2[7+k], t1);
    d1 = fmaf(o[7+k], attd2[7+k], d1);
  }
  // head rows: {o0..o6, as2_h} packed fp16 into one float4 each
  float4 rA, rB;
  rA.x = __builtin_bit_cast(float, __floats2half2_rn(o[0], o[1]));
  rA.y = __builtin_bit_cast(float, __floats2half2_rn(o[2], o[3]));
  rA.z = __builtin_bit_cast(float, __floats2half2_rn(o[4], o[5]));
  rA.w = __builtin_bit_cast(float, __floats2half2_rn(o[6], t0));
  rB.x = __builtin_bit_cast(float, __floats2half2_rn(o[7], o[8]));
  rB.y = __builtin_bit_cast(float, __floats2half2_rn(o[9], o[10]));
  rB.z = __builtin_bit_cast(float, __floats2half2_rn(o[11], o[12]));
  rB.w = __builtin_bit_cast(float, __floats2half2_rn(o[13], t1));
  xl2p[2*i]   = rA;
  xl2p[2*i+1] = rB;
  ad2[2*i] = d0; ad2[2*i+1] = d1;
}

// -- L2 gather + finalize: 2 lanes/node (1 per head), as packed in row ------
__global__ void k_gather_final(const unsigned* __restrict__ rp,
                               const int* __restrict__ col,
                               const float4* __restrict__ xl2p, // [N,2]
                               const float* __restrict__ ad2,   // [N,2]
                               const float* __restrict__ b2,    // [7]
                               float* __restrict__ out,         // [N,7]
                               int n, int E) {
  int idx = blockIdx.x * blockDim.x + threadIdx.x;
  int d = idx >> 1;
  int h = idx & 1;
  if (d >= n) return;
  float adh = ad2[2*d + h];
  float acc[7] = {0.f,0.f,0.f,0.f,0.f,0.f,0.f};
  float den = 0.f;

  auto proc = [&](float4 r) {
    float2 c01 = h2f(r.x), c23 = h2f(r.y), c45 = h2f(r.z), c6a = h2f(r.w);
    float a = c6a.y + adh; a = (a >= 0.f) ? a : NEG_SLOPE*a;
    float e = __expf(a);
    acc[0] = fmaf(c01.x, e, acc[0]); acc[1] = fmaf(c01.y, e, acc[1]);
    acc[2] = fmaf(c23.x, e, acc[2]); acc[3] = fmaf(c23.y, e, acc[3]);
    acc[4] = fmaf(c45.x, e, acc[4]); acc[5] = fmaf(c45.y, e, acc[5]);
    acc[6] = fmaf(c6a.x, e, acc[6]); den += e;
  };

  unsigned jb = rp[d];
  unsigned je = (d + 1 < n) ? rp[d + 1] : (unsigned)E;
  unsigned j = jb;
  for (; j + 4 <= je; j += 4) {
    int s0 = col[j], s1 = col[j+1], s2 = col[j+2], s3 = col[j+3];
    float4 r0 = xl2p[2*(size_t)s0 + h];
    float4 r1 = xl2p[2*(size_t)s1 + h];
    float4 r2 = xl2p[2*(size_t)s2 + h];
    float4 r3 = xl2p[2*(size_t)s3 + h];
    proc(r0); proc(r1); proc(r2); proc(r3);
  }
  for (; j < je; ++j) proc(xl2p[2*(size_t)col[j] + h]);
  proc(xl2p[2*(size_t)d + h]);   // self-loop

  float inv = 1.f / (den + 1e-16f);
  float v[7];
#pragma unroll
  for (int c = 0; c < 7; ++c) {
    float mine = acc[c] * inv;
    float other = __shfl_xor(mine, 1, 2);      // other head, same node
    v[c] = 0.5f * (mine + other) + b2[c];
  }
  float m = v[0];
#pragma unroll
  for (int c = 1; c < 7; ++c) m = fmaxf(m, v[c]);
  float s = 0.f;
#pragma unroll
  for (int c = 0; c < 7; ++c) s += __expf(v[c] - m);
  float ls = __logf(s);
  float* o = out + (size_t)d * 7;
  if (h == 0) {
    o[0] = v[0]-m-ls; o[1] = v[1]-m-ls; o[2] = v[2]-m-ls; o[3] = v[3]-m-ls;
  } else {
    o[4] = v[4]-m-ls; o[5] = v[5]-m-ls; o[6] = v[6]-m-ls;
  }
}

extern "C" void kernel_launch(void* const* d_in, const int* in_sizes, int n_in,
                              void* d_out, int out_size, void* d_ws, size_t ws_size,
                              hipStream_t stream) {
  const float* x    = (const float*)d_in[0];
  const int*   ei   = (const int*)  d_in[1];
  const float* w1   = (const float*)d_in[2];
  const float* as1w = (const float*)d_in[3];
  const float* ad1w = (const float*)d_in[4];
  const float* b1   = (const float*)d_in[5];
  const float* w2   = (const float*)d_in[6];
  const float* as2w = (const float*)d_in[7];
  const float* ad2w = (const float*)d_in[8];
  const float* b2   = (const float*)d_in[9];
  float* out = (float*)d_out;

  const int n = in_sizes[0] / 3;
  const int E = in_sizes[1] / 2;
  const int* esrc = ei;
  const int* edst = ei + E;
  const int nb = (n + BNODES - 1) >> BUCKET_BITS;   // 782 for n=100000

  const size_t Na = ((size_t)n + 3) & ~(size_t)3;   // 16B-aligned node stride
  float* ws = (float*)d_ws;
  // workspace layout (4-byte units):
  float4* xp    = (float4*)ws;                      //  4Na  packed x+as rows
  float*  ad1   = ws + 4*Na;                        //  2Na
  float4* numx  = (float4*)(ws + 6*Na);             //  8Na
  float4* xl2p  = (float4*)(ws + 14*Na);            //  8Na
  float*  ad2   = ws + 22*Na;                       //  2Na -> 24Na
  unsigned* ctrl   = (unsigned*)(ws + 24*Na);
  unsigned* gcount = ctrl;                          // MAXNB+1
  unsigned* bstart = ctrl + (MAXNB + 1);            // MAXNB+1
  unsigned* bcur   = ctrl + 2*(MAXNB + 1);          // MAXNB+1
  unsigned* sstart = ctrl + 3*(MAXNB + 1);          // MAXSUP+1
  unsigned* scur   = sstart + (MAXSUP + 1);         // MAXSUP
  unsigned* rp     = scur + MAXSUP;                 // Na
  int*      col    = (int*)(rp + Na);               // E
  unsigned* packed2= (unsigned*)(col + E);          // E
  unsigned* tmp1   = packed2 + E;                   // E

  const int nbN = (n + 255) / 256;
  const int nbC = (E + CHUNK - 1) / CHUNK;

  hipMemsetAsync(gcount, 0, (MAXNB + 1) * sizeof(unsigned), stream);

  k_node1<<<nbN, 256, 0, stream>>>(x, w1, as1w, ad1w, xp, ad1, n);

  // two-level radix CSR build (shared by both layers)
  k_hist1024<<<512, 256, 0, stream>>>(edst, gcount, E, nb);
  k_scanall <<<1, MAXNB, 0, stream>>>(gcount, bstart, bcur, sstart, scur, nb);
  k_part1   <<<nbC, PTHREADS, 0, stream>>>(esrc, edst, scur, tmp1, E);
  k_part2   <<<nbC, PTHREADS, 0, stream>>>(tmp1, sstart, bcur, packed2, E, nb);
  k_sortb   <<<nb, 256, 0, stream>>>(bstart, packed2, col, rp, n);

  // Layer 1: x-space gather, 1 lane/node, both heads (table 1.6 MB, L2-resident)
  k_gatherX<<<nbN, 256, 0, stream>>>(rp, col, xp, ad1, numx, n, E);
  k_node2<<<nbN, 256, 0, stream>>>(x, numx, ad1, w1, as1w, ad1w, b1, w2,
                                   as2w, ad2w, xl2p, ad2, n);

  // Layer 2: 2 lanes/node (1 per head), as packed in row (table 3.2 MB)
  k_gather_final<<<(2*n + 255)/256, 256, 0, stream>>>(
      rp, col, xl2p, ad2, b2, out, n, E);
}